// Round 4
// baseline (359.289 us; speedup 1.0000x reference)
//
#include <hip/hip_runtime.h>
#include <hip/hip_bf16.h>
#include <math.h>

typedef __attribute__((ext_vector_type(8))) short bf16x8;
typedef __attribute__((ext_vector_type(4))) short bf16x4;
typedef __attribute__((ext_vector_type(4))) float f32x4;

#define NB 4096
#define ND 1024
#define INV_T 14.2857142857142857f   // 1/0.07

__device__ inline unsigned short f2bf(float x) {
    __hip_bfloat16 h = __float2bfloat16(x);
    return *reinterpret_cast<unsigned short*>(&h);
}
__device__ inline float bf2f(unsigned short u) {
    unsigned v = ((unsigned)u) << 16;
    return __uint_as_float(v);
}
__device__ inline void gload16(const void* g, void* l) {
    __builtin_amdgcn_global_load_lds(
        (const __attribute__((address_space(1))) void*)g,
        (__attribute__((address_space(3))) void*)l, 16, 0, 0);
}

// ---------------- kernel 0: L2-normalize rows, cast to bf16 -----------------
__global__ __launch_bounds__(256) void norm_kernel(
        const float* __restrict__ M, const float* __restrict__ P,
        __hip_bfloat16* __restrict__ Mn, __hip_bfloat16* __restrict__ Pn) {
    int row = blockIdx.x & (NB - 1);
    const float* src = (blockIdx.x < NB) ? M : P;
    __hip_bfloat16* dst = (blockIdx.x < NB) ? Mn : Pn;
    int tid = threadIdx.x;
    float4 v = ((const float4*)(src + (size_t)row * ND))[tid];
    float ss = v.x * v.x + v.y * v.y + v.z * v.z + v.w * v.w;
    for (int off = 32; off; off >>= 1) ss += __shfl_down(ss, off);
    __shared__ float red[4];
    int lane = tid & 63, w = tid >> 6;
    if (lane == 0) red[w] = ss;
    __syncthreads();
    float rn = rsqrtf(red[0] + red[1] + red[2] + red[3]);
    ushort4 o;
    o.x = f2bf(v.x * rn); o.y = f2bf(v.y * rn);
    o.z = f2bf(v.z * rn); o.w = f2bf(v.w * rn);
    *(ushort4*)((unsigned short*)dst + (size_t)row * ND + tid * 4) = o;
}

// ---------------- kernel 1: per-row mask codes ------------------------------
__global__ __launch_bounds__(256) void key_kernel(
        const int* __restrict__ labels, const int* __restrict__ sm,
        const int* __restrict__ sp, int* __restrict__ code) {
    int i = blockIdx.x * 256 + threadIdx.x;
    if (i < NB) {
        int l = labels[i];
        code[i] = (l == 0) ? 0x40000000 : (1 + l + (sm[i] << 8) + (sp[i] << 16));
    }
}

// ------- kernel 2: fused row-sum + normalized masked weight matrix (bf16) ---
__global__ __launch_bounds__(256) void rowsumw_kernel(
        const float* __restrict__ cs, const int* __restrict__ code,
        unsigned short* __restrict__ W, float* __restrict__ flag) {
    int i = blockIdx.x;
    int ci = code[i];
    int tid = threadIdx.x;
    const float4* row = (const float4*)(cs + (size_t)i * NB);
    const int4* c4 = (const int4*)code;
    float4 v[4];
    int4 cj[4];
    float s = 0.f;
#pragma unroll
    for (int k = 0; k < 4; ++k) {
        int t = tid + k * 256;
        v[k] = row[t];
        cj[k] = c4[t];
        int j = t * 4;
        if (cj[k].x == ci && j + 0 != i) s += v[k].x;
        if (cj[k].y == ci && j + 1 != i) s += v[k].y;
        if (cj[k].z == ci && j + 2 != i) s += v[k].z;
        if (cj[k].w == ci && j + 3 != i) s += v[k].w;
    }
    for (int off = 1; off < 64; off <<= 1) s += __shfl_xor(s, off);
    __shared__ float red[4];
    int lane = tid & 63, w = tid >> 6;
    if (lane == 0) red[w] = s;
    __syncthreads();
    float tot = red[0] + red[1] + red[2] + red[3];
    float inv = (tot > 0.f) ? 1.f / tot : 0.f;
#pragma unroll
    for (int k = 0; k < 4; ++k) {
        int t = tid + k * 256;
        int j = t * 4;
        ushort4 o;
        o.x = (cj[k].x == ci && j + 0 != i) ? f2bf(v[k].x * inv) : (unsigned short)0;
        o.y = (cj[k].y == ci && j + 1 != i) ? f2bf(v[k].y * inv) : (unsigned short)0;
        o.z = (cj[k].z == ci && j + 2 != i) ? f2bf(v[k].z * inv) : (unsigned short)0;
        o.w = (cj[k].w == ci && j + 3 != i) ? f2bf(v[k].w * inv) : (unsigned short)0;
        *(ushort4*)&W[(size_t)i * NB + j] = o;
    }
    if (tid == 0) flag[i] = (tot > 0.f) ? 1.f : 0.f;
}

// ---------------- kernel 3: fused 256x256-tile GEMM + loss epilogue ---------
// 528 blocks: b<256 -> cross (S1 = Mn Pn^T, 16x16 grid).
//             b>=256 -> symmetric (Mn or Pn), upper-tri 16x16 (136 each).
// 512 threads = 8 waves (2 x 4); wave tile 128x64; acc[8][4] 16x16 frags.
// BK=32 double-buffered, global_load_lds staging, 64 KB LDS.
__global__ __launch_bounds__(512, 2) void mega_gemm(
        const __hip_bfloat16* __restrict__ Mn, const __hip_bfloat16* __restrict__ Pn,
        const unsigned short* __restrict__ Wg,
        float* __restrict__ rowsum1, float* __restrict__ colsum1,
        float* __restrict__ rowsum3, float* __restrict__ rowsum4,
        float* __restrict__ dots) {
    __shared__ char smem[65536] __attribute__((aligned(16)));

    int tid = threadIdx.x;
    int lane = tid & 63, w = tid >> 6;
    int wm = w >> 2, wn = w & 3;
    int lr = lane & 15, lg = lane >> 4;

    // ---- block decode ----
    int b = blockIdx.x;
    int bi, bj, mode;
    const __hip_bfloat16 *A, *Bm;
    if (b < 256) {
        bi = b >> 4; bj = b & 15; A = Mn; Bm = Pn; mode = 0;
    } else {
        int t = b - 256;
        int md = (t >= 136) ? 1 : 0;
        t -= md * 136;
        bi = 0;
        while (t >= 16 - bi) { t -= 16 - bi; ++bi; }
        bj = bi + t;
        A = md ? Pn : Mn; Bm = A;
        mode = 1 + md;
    }
    bool offdiag = (mode == 0) || (bi != bj);
    size_t rowBase = (size_t)bi * 256;
    size_t colBase = (size_t)bj * 256;
    float* rowTgt = (mode == 0) ? rowsum1 : ((mode == 1) ? rowsum3 : rowsum4);
    float* colTgt = (mode == 0) ? colsum1 : rowTgt;

    // ---- main K loop: BK=32, double-buffered ----
    // staging: per operand 16 issues of 1KB (16 rows x 64B); wave w: issues 2w,2w+1
    int srow0 = w * 32 + (lane >> 2);          // + c*16
    int sch = (lane & 3) * 8;                  // 16B chunk within 64B row
    const __hip_bfloat16* gA = A + (rowBase + srow0) * ND + sch;
    const __hip_bfloat16* gB = Bm + (colBase + srow0) * ND + sch;

    f32x4 acc[8][4] = {};

#define STAGE(buf, t) {                                                   \
        int k0 = (t) * 32;                                                \
        char* base = smem + (buf) * 32768;                                \
        gload16(gA + k0,           base + (w * 2    ) * 1024);            \
        gload16(gA + 16 * ND + k0, base + (w * 2 + 1) * 1024);            \
        gload16(gB + k0,           base + 16384 + (w * 2    ) * 1024);    \
        gload16(gB + 16 * ND + k0, base + 16384 + (w * 2 + 1) * 1024);    \
    }

    STAGE(0, 0);
    __syncthreads();
    int cur = 0;
    for (int t = 0; t < 32; ++t) {
        if (t < 31) STAGE(cur ^ 1, t + 1);
        const __hip_bfloat16* sA = (const __hip_bfloat16*)(smem + cur * 32768);
        const __hip_bfloat16* sB = sA + 8192;
        bf16x8 av[8], bv[4];
#pragma unroll
        for (int m = 0; m < 8; ++m)
            av[m] = *(const bf16x8*)&sA[(wm * 128 + m * 16 + lr) * 32 + lg * 8];
#pragma unroll
        for (int n = 0; n < 4; ++n)
            bv[n] = *(const bf16x8*)&sB[(wn * 64 + n * 16 + lr) * 32 + lg * 8];
#pragma unroll
        for (int m = 0; m < 8; ++m)
#pragma unroll
            for (int n = 0; n < 4; ++n)
                acc[m][n] = __builtin_amdgcn_mfma_f32_16x16x32_bf16(
                    av[m], bv[n], acc[m][n], 0, 0, 0);
        __syncthreads();
        cur ^= 1;
    }
#undef STAGE

    // ---- epilogue ----
    unsigned short* wl = (unsigned short*)smem;
    float d1 = 0.f, d2 = 0.f;
    float cexp[4] = {0.f, 0.f, 0.f, 0.f};

    // d1 + rexp + cexp, two 64KB halves of the W[i][j] tile (128 rows x 256)
#pragma unroll
    for (int h = 0; h < 2; ++h) {
        // stage: 64 issues of 1KB; issue idx q covers LDS rows 2q,2q+1 (512B rows)
#pragma unroll
        for (int c = 0; c < 8; ++c) {
            int q = w * 8 + c;
            int srow = 2 * q + (lane >> 5);                 // LDS row 0..127
            int gchunk = (lane & 31) ^ (srow & 7);          // source pre-swizzle
            int grow = ((srow >> 6) << 7) + h * 64 + (srow & 63);
            gload16(Wg + (rowBase + grow) * (size_t)NB + colBase + gchunk * 8,
                    smem + q * 1024);
        }
        __syncthreads();
#pragma unroll
        for (int mm = 0; mm < 4; ++mm) {
            int m = h * 4 + mm;
            float rexp[4] = {0.f, 0.f, 0.f, 0.f};
#pragma unroll
            for (int n = 0; n < 4; ++n) {
                int jl = wn * 64 + n * 16 + lr;
#pragma unroll
                for (int r = 0; r < 4; ++r) {
                    int rl = wm * 64 + mm * 16 + lg * 4 + r;   // LDS row
                    float sim = acc[m][n][r] * INV_T;
                    float e = __expf(sim - INV_T);
                    rexp[r] += e;
                    cexp[n] += e;
                    int ck = (jl >> 3) ^ (rl & 7);
                    d1 += bf2f(wl[rl * 256 + ck * 8 + (jl & 7)]) * sim;
                }
            }
#pragma unroll
            for (int r = 0; r < 4; ++r) {
                float v = rexp[r];
                v += __shfl_xor(v, 1); v += __shfl_xor(v, 2);
                v += __shfl_xor(v, 4); v += __shfl_xor(v, 8);
                if (lr == 0)
                    atomicAdd(&rowTgt[rowBase + wm * 128 + m * 16 + lg * 4 + r], v);
            }
        }
        __syncthreads();
    }

    if (offdiag) {
#pragma unroll
        for (int n = 0; n < 4; ++n) {
            float v = cexp[n];
            v += __shfl_xor(v, 16); v += __shfl_xor(v, 32);
            if (lg == 0)
                atomicAdd(&colTgt[colBase + wn * 64 + n * 16 + lr], v);
        }
        // d2: W[j][i] tile in two halves by i: [jl 0..255][128 cols], 256B rows
#pragma unroll
        for (int h = 0; h < 2; ++h) {
#pragma unroll
            for (int c = 0; c < 8; ++c) {
                int q = w * 8 + c;
                int srow = 4 * q + (lane >> 4);             // jl row 0..255
                int gchunk = (lane & 15) ^ (srow & 7);
                gload16(Wg + (colBase + srow) * (size_t)NB + rowBase + h * 128 + gchunk * 8,
                        smem + q * 1024);
            }
            __syncthreads();
            if (wm == h) {
#pragma unroll
                for (int m = 0; m < 8; ++m) {
                    int il = m * 16 + lg * 4;
#pragma unroll
                    for (int n = 0; n < 4; ++n) {
                        int jl = wn * 64 + n * 16 + lr;
                        int ck = (il >> 3) ^ (jl & 7);
                        bf16x4 wv = *(const bf16x4*)&wl[jl * 128 + ck * 8 + (il & 7)];
#pragma unroll
                        for (int r = 0; r < 4; ++r)
                            d2 += bf2f((unsigned short)wv[r]) * (acc[m][n][r] * INV_T);
                    }
                }
            }
            __syncthreads();
        }
    }

    if (mode == 0) {
        for (int off = 32; off; off >>= 1) {
            d1 += __shfl_xor(d1, off);
            d2 += __shfl_xor(d2, off);
        }
        if (lane == 0) {
            atomicAdd(&dots[0], d1);
            atomicAdd(&dots[1], d2);
        }
    } else {
        float dtot = d1 + (offdiag ? d2 : 0.f);
        for (int off = 32; off; off >>= 1) dtot += __shfl_xor(dtot, off);
        if (lane == 0) atomicAdd(&dots[1 + mode], dtot);
    }
}

// ---------------- kernel 4: finalize --------------------------------------
__global__ __launch_bounds__(256) void finalize_kernel(
        const float* __restrict__ rowsum1, const float* __restrict__ colsum1,
        const float* __restrict__ rowsum3, const float* __restrict__ rowsum4,
        const float* __restrict__ flag, const float* __restrict__ dots,
        float* __restrict__ out) {
    int tid = threadIdx.x;
    float l = 0.f;
    for (int i = tid; i < NB; i += 256) {
        if (flag[i] != 0.f) {
            l += 4.f * INV_T + logf(rowsum1[i]) + logf(colsum1[i]) +
                 logf(rowsum3[i]) + logf(rowsum4[i]);
        }
    }
    for (int off = 32; off; off >>= 1) l += __shfl_down(l, off);
    __shared__ float red[4];
    int lane = tid & 63, w = tid >> 6;
    if (lane == 0) red[w] = l;
    __syncthreads();
    if (tid == 0) {
        float L = red[0] + red[1] + red[2] + red[3];
        float dt = dots[0] + dots[1] + dots[2] + dots[3];
        out[0] = (L - dt) / (4.0f * (float)NB);
    }
}

extern "C" void kernel_launch(void* const* d_in, const int* in_sizes, int n_in,
                              void* d_out, int out_size, void* d_ws, size_t ws_size,
                              hipStream_t stream) {
    const float* M = (const float*)d_in[0];
    const float* P = (const float*)d_in[1];
    const int* labels = (const int*)d_in[2];
    const int* sm = (const int*)d_in[3];
    const int* sp = (const int*)d_in[4];
    const float* cs = (const float*)d_in[5];
    float* out = (float*)d_out;

    char* ws = (char*)d_ws;
    __hip_bfloat16* Mn = (__hip_bfloat16*)ws;                              // 8 MB
    __hip_bfloat16* Pn = (__hip_bfloat16*)(ws + (size_t)8 * 1024 * 1024);  // 8 MB
    unsigned short* W = (unsigned short*)(ws + (size_t)16 * 1024 * 1024);  // 32 MB
    char* p = ws + (size_t)48 * 1024 * 1024;
    int* code = (int*)p;        p += 16384;
    float* flag = (float*)p;    p += 16384;
    float* rowsum1 = (float*)p; p += 16384;
    float* colsum1 = (float*)p; p += 16384;
    float* rowsum3 = (float*)p; p += 16384;
    float* rowsum4 = (float*)p; p += 16384;
    float* dots = (float*)p;

    hipMemsetAsync(rowsum1, 0, 4 * 16384 + 256, stream);

    norm_kernel<<<2 * NB, 256, 0, stream>>>(M, P, Mn, Pn);
    key_kernel<<<NB / 256, 256, 0, stream>>>(labels, sm, sp, code);
    rowsumw_kernel<<<NB, 256, 0, stream>>>(cs, code, W, flag);

    mega_gemm<<<528, 512, 0, stream>>>(Mn, Pn, W, rowsum1, colsum1,
                                       rowsum3, rowsum4, dots);

    finalize_kernel<<<1, 256, 0, stream>>>(rowsum1, colsum1, rowsum3, rowsum4,
                                           flag, dots, out);
}